// Round 5
// baseline (388.849 us; speedup 1.0000x reference)
//
#include <hip/hip_runtime.h>
#include <hip/hip_bf16.h>

typedef __bf16 bf16x8 __attribute__((ext_vector_type(8)));
typedef __bf16 bf16x4 __attribute__((ext_vector_type(4)));
typedef float floatx4 __attribute__((ext_vector_type(4)));

typedef __attribute__((address_space(1))) const void gas_void;
typedef __attribute__((address_space(3))) void las_void;

__device__ inline void async_load16(const void* g, void* l) {
  __builtin_amdgcn_global_load_lds((gas_void*)g, (las_void*)l, 16, 0, 0);
}

// ---- fp32 -> bf16 elementwise convert (n4 = count of float4 groups) ----
__global__ __launch_bounds__(256) void f32_to_bf16_kernel(const float* __restrict__ in,
                                                          __bf16* __restrict__ out, int n4) {
  int i = blockIdx.x * 256 + threadIdx.x;
  if (i < n4) {
    float4 v = ((const float4*)in)[i];
    bf16x4 o = {(__bf16)v.x, (__bf16)v.y, (__bf16)v.z, (__bf16)v.w};
    ((bf16x4*)out)[i] = o;
  }
}

// ---- V [4096][1024] fp32 -> Vt [1024][4096] bf16 ----
__global__ __launch_bounds__(256) void transpose_convert_kernel(const float* __restrict__ V,
                                                                __bf16* __restrict__ Vt) {
  __shared__ float tile[64][65];
  const int bx = blockIdx.x;  // p tile
  const int by = blockIdx.y;  // e tile
  for (int i = threadIdx.x; i < 64 * 64; i += 256) {
    const int r = i >> 6, c = i & 63;
    tile[r][c] = V[(size_t)(bx * 64 + r) * 1024 + by * 64 + c];
  }
  __syncthreads();
  for (int i = threadIdx.x; i < 64 * 64; i += 256) {
    const int r = i >> 6, c = i & 63;
    Vt[(size_t)(by * 64 + r) * 4096 + bx * 64 + c] = (__bf16)tile[c][r];
  }
}

// C = A (MxK bf16, k-contig) x B (N rows of K bf16, k-contig). 128x128 tile, BK=32.
// LDS layout is q-major: 16-B unit (row m, k-chunk q) at offset (q*128 + m)*16
// -> fragment ds_read_b128 walks consecutive units across lanes 0-15: 2-way
// bank aliasing only (free), vs 8-way with row-major 64-B rows.
// Flat-1D grid + XCD swizzle (id%8 = XCD): blocks sharing an A m-tile share an XCD.
// MODE 0: P[m,n] = exp(min(dot/32,30)) -> bf16 Cb; fused row-sum atomicAdd into lsum.
// MODE 1: out[m,n] = dot / lsum[m] -> fp32 Cf.
template <int MODE, int KS, int NS>
__global__ __launch_bounds__(256) void gemm_kernel(const __bf16* __restrict__ A,
                                                   const __bf16* __restrict__ B,
                                                   __bf16* __restrict__ Cb,
                                                   float* __restrict__ Cf,
                                                   float* __restrict__ lsum) {
  constexpr int BK = 32;
  __shared__ __bf16 As[128 * BK];  // 8 KiB
  __shared__ __bf16 Bs[128 * BK];  // 8 KiB
  const int t = threadIdx.x;
  const int lane = t & 63;
  const int w = t >> 6;
  const int wr = w >> 1, wc = w & 1;

  // XCD-aware swizzle: 64 m-tiles, NS/128 n-tiles.
  const int id = blockIdx.x;
  const int g = id & 7;
  const int s = id >> 3;
  const int mt = g * 8 + (s & 7);
  const int nt = s >> 3;
  const int m0 = mt * 128;
  const int n0 = nt * 128;

  const __bf16* Ab = A + (size_t)m0 * KS;
  const __bf16* Bb = B + (size_t)n0 * KS;

  floatx4 acc[4][4] = {};

  // staging (q-major): thread t, round r stages unit u = t + r*256 of the
  // operand tile; (m = u&127, q = u>>7); LDS dst offset = u*16 (HW-forced).
  const int mA = t & 127;
  const int q0 = t >> 7;  // 0..1
  const __bf16* a0 = Ab + (size_t)mA * KS + q0 * 8;        // rounds 0: q = 0..1
  const __bf16* a1 = Ab + (size_t)mA * KS + (q0 + 2) * 8;  // round 1: q = 2..3
  const __bf16* b0 = Bb + (size_t)mA * KS + q0 * 8;
  const __bf16* b1 = Bb + (size_t)mA * KS + (q0 + 2) * 8;
  char* dA0 = (char*)As + t * 16;
  char* dA1 = (char*)As + t * 16 + 4096;
  char* dB0 = (char*)Bs + t * 16;
  char* dB1 = (char*)Bs + t * 16 + 4096;

  for (int k0 = 0; k0 < KS; k0 += BK) {
    async_load16(a0 + k0, dA0);
    async_load16(a1 + k0, dA1);
    async_load16(b0 + k0, dB0);
    async_load16(b1 + k0, dB1);
    __builtin_amdgcn_s_waitcnt(0);
    __syncthreads();

    bf16x8 aF[4], bF[4];
    const int qb = (lane >> 4) << 11;  // q * 128 units * 16 B
#pragma unroll
    for (int i = 0; i < 4; ++i) {
      const int mr = wr * 64 + i * 16 + (lane & 15);
      aF[i] = *(const bf16x8*)((const char*)As + qb + mr * 16);
    }
#pragma unroll
    for (int j = 0; j < 4; ++j) {
      const int nr = wc * 64 + j * 16 + (lane & 15);
      bF[j] = *(const bf16x8*)((const char*)Bs + qb + nr * 16);
    }
#pragma unroll
    for (int i = 0; i < 4; ++i)
#pragma unroll
      for (int j = 0; j < 4; ++j)
        acc[i][j] = __builtin_amdgcn_mfma_f32_16x16x32_bf16(aF[i], bF[j], acc[i][j], 0, 0, 0);
    __syncthreads();
  }

  // C/D layout: col = lane&15, row = (lane>>4)*4 + reg
  const int cm = wr * 64 + ((lane >> 4) << 2);
  const int cn = wc * 64 + (lane & 15);
  if (MODE == 0) {
#pragma unroll
    for (int i = 0; i < 4; ++i)
#pragma unroll
      for (int r = 0; r < 4; ++r) {
        const int m = m0 + cm + i * 16 + r;
        float rs = 0.f;
#pragma unroll
        for (int j = 0; j < 4; ++j) {
          const float e = __expf(fminf(acc[i][j][r] * 0.03125f, 30.0f));
          rs += e;
          Cb[(size_t)m * NS + n0 + cn + j * 16] = (__bf16)e;
        }
        rs += __shfl_xor(rs, 1, 64);
        rs += __shfl_xor(rs, 2, 64);
        rs += __shfl_xor(rs, 4, 64);
        rs += __shfl_xor(rs, 8, 64);
        if ((lane & 15) == 0) atomicAdd(&lsum[m], rs);
      }
  } else {
#pragma unroll
    for (int i = 0; i < 4; ++i)
#pragma unroll
      for (int r = 0; r < 4; ++r) {
        const int m = m0 + cm + i * 16 + r;
        const float inv = 1.0f / lsum[m];
#pragma unroll
        for (int j = 0; j < 4; ++j)
          Cf[(size_t)m * NS + n0 + cn + j * 16] = acc[i][j][r] * inv;
      }
  }
}

extern "C" void kernel_launch(void* const* d_in, const int* in_sizes, int n_in,
                              void* d_out, int out_size, void* d_ws, size_t ws_size,
                              hipStream_t stream) {
  const float* x = (const float*)d_in[0];  // [8192][1024] fp32
  const float* K = (const float*)d_in[1];  // [4096][1024] fp32
  const float* V = (const float*)d_in[2];  // [4096][1024] fp32
  float* out = (float*)d_out;              // [8192][1024] fp32

  char* ws = (char*)d_ws;
  __bf16* xb = (__bf16*)ws;                        // 16 MiB
  __bf16* Kb = (__bf16*)(ws + (16u << 20));        // 8 MiB
  __bf16* Vt = (__bf16*)(ws + (24u << 20));        // 8 MiB
  __bf16* P  = (__bf16*)(ws + (32u << 20));        // 64 MiB
  float*  l  = (float*)(ws + (96u << 20));         // 32 KiB

  f32_to_bf16_kernel<<<8192, 256, 0, stream>>>(x, xb, 8192 * 1024 / 4);
  f32_to_bf16_kernel<<<4096, 256, 0, stream>>>(K, Kb, 4096 * 1024 / 4);
  transpose_convert_kernel<<<dim3(64, 16), 256, 0, stream>>>(V, Vt);
  hipMemsetAsync(l, 0, 8192 * sizeof(float), stream);
  // P = exp(xb @ Kb^T / 32), fused row sums  (M=8192 N=4096 K=1024), 2048 blocks
  gemm_kernel<0, 1024, 4096><<<2048, 256, 0, stream>>>(xb, Kb, P, nullptr, l);
  // out = (P @ Vt-rows) / l  (M=8192 N=1024 K=4096), 512 blocks
  gemm_kernel<1, 4096, 1024><<<512, 256, 0, stream>>>(P, Vt, nullptr, out, l);
}

// Round 6
// 282.626 us; speedup vs baseline: 1.3758x; 1.3758x over previous
//
#include <hip/hip_runtime.h>
#include <hip/hip_bf16.h>

typedef __bf16 bf16x8 __attribute__((ext_vector_type(8)));
typedef __bf16 bf16x4 __attribute__((ext_vector_type(4)));
typedef float floatx4 __attribute__((ext_vector_type(4)));

typedef __attribute__((address_space(1))) const void gas_void;
typedef __attribute__((address_space(3))) void las_void;

__device__ inline void async_load16(const void* g, void* l) {
  __builtin_amdgcn_global_load_lds((gas_void*)g, (las_void*)l, 16, 0, 0);
}

// ---- fp32 -> bf16 elementwise convert ----
__global__ __launch_bounds__(256) void f32_to_bf16_kernel(const float* __restrict__ in,
                                                          __bf16* __restrict__ out, int n4) {
  int i = blockIdx.x * 256 + threadIdx.x;
  if (i < n4) {
    float4 v = ((const float4*)in)[i];
    bf16x4 o = {(__bf16)v.x, (__bf16)v.y, (__bf16)v.z, (__bf16)v.w};
    ((bf16x4*)out)[i] = o;
  }
}

// ---- V [4096][1024] fp32 -> Vt [1024][4096] bf16 ----
__global__ __launch_bounds__(256) void transpose_convert_kernel(const float* __restrict__ V,
                                                                __bf16* __restrict__ Vt) {
  __shared__ float tile[64][65];
  const int bx = blockIdx.x;
  const int by = blockIdx.y;
  for (int i = threadIdx.x; i < 64 * 64; i += 256) {
    const int r = i >> 6, c = i & 63;
    tile[r][c] = V[(size_t)(bx * 64 + r) * 1024 + by * 64 + c];
  }
  __syncthreads();
  for (int i = threadIdx.x; i < 64 * 64; i += 256) {
    const int r = i >> 6, c = i & 63;
    Vt[(size_t)(by * 64 + r) * 4096 + bx * 64 + c] = (__bf16)tile[c][r];
  }
}

// C = A (MxK bf16, k-contig) x B (N rows of K bf16, k-contig). 128x128 tile, BK=32.
// LDS: XOR-swizzled m-major layout. 16-B unit (row m, k-chunk q) lives at unit
// index 4m + (q ^ (m&3) ^ ((m>>2)&3)).
//  - staging thread t stages unit t (m=t>>2): sources chunk q=(t&3)^(m&3)^((m>>2)&3);
//    4-lane groups still cover contiguous 64-B row segments -> coalesced.
//  - fragment read lane L hits bank-group (unit mod 8) exactly 2x per
//    quarter-wave -> 2-way aliasing = free (m136).
// Flat-1D grid + XCD swizzle (id%8 = XCD): blocks sharing an A m-tile share an XCD.
// MODE 0: P = exp(min(dot/32,30)) -> bf16 Cb + fused row-sum atomicAdd into lsum.
// MODE 1: out = dot / lsum[m] -> fp32 Cf.
template <int MODE, int KS, int NS>
__global__ __launch_bounds__(256) void gemm_kernel(const __bf16* __restrict__ A,
                                                   const __bf16* __restrict__ B,
                                                   __bf16* __restrict__ Cb,
                                                   float* __restrict__ Cf,
                                                   float* __restrict__ lsum) {
  constexpr int BK = 32;
  __shared__ __bf16 As[128 * BK];  // 8 KiB
  __shared__ __bf16 Bs[128 * BK];  // 8 KiB
  const int t = threadIdx.x;
  const int lane = t & 63;
  const int w = t >> 6;
  const int wr = w >> 1, wc = w & 1;

  // XCD-aware swizzle: 64 m-tiles, NS/128 n-tiles.
  const int id = blockIdx.x;
  const int g = id & 7;
  const int s = id >> 3;
  const int mt = g * 8 + (s & 7);
  const int nt = s >> 3;
  const int m0 = mt * 128;
  const int n0 = nt * 128;

  const __bf16* Ab = A + (size_t)m0 * KS;
  const __bf16* Bb = B + (size_t)n0 * KS;

  floatx4 acc[4][4] = {};

  // staging: round r, thread t -> LDS unit u = r*256+t; m = u>>2 (round1: +64),
  // source chunk q = (t&3)^(m&3)^((m>>2)&3)  (same q both rounds).
  const int mlo = t >> 2;
  const int qs = (t & 3) ^ (mlo & 3) ^ ((mlo >> 2) & 3);
  const __bf16* a0 = Ab + (size_t)mlo * KS + qs * 8;
  const __bf16* a1 = Ab + (size_t)(64 + mlo) * KS + qs * 8;
  const __bf16* b0 = Bb + (size_t)mlo * KS + qs * 8;
  const __bf16* b1 = Bb + (size_t)(64 + mlo) * KS + qs * 8;
  char* dA0 = (char*)As + t * 16;
  char* dA1 = (char*)As + t * 16 + 4096;
  char* dB0 = (char*)Bs + t * 16;
  char* dB1 = (char*)Bs + t * 16 + 4096;

  // fragment read offsets: lane L (rl = L&15, qq = L>>4) reads unit 4m+sw
  const int rl = lane & 15;
  const int qq = lane >> 4;
  const int sw = qq ^ (rl & 3) ^ ((rl >> 2) & 3);
  const int fidx = (4 * rl + sw) * 16;  // byte offset within a 16-row group

  for (int k0 = 0; k0 < KS; k0 += BK) {
    async_load16(a0 + k0, dA0);
    async_load16(a1 + k0, dA1);
    async_load16(b0 + k0, dB0);
    async_load16(b1 + k0, dB1);
    __builtin_amdgcn_s_waitcnt(0);
    __syncthreads();

    bf16x8 aF[4], bF[4];
#pragma unroll
    for (int i = 0; i < 4; ++i)
      aF[i] = *(const bf16x8*)((const char*)As + wr * 4096 + i * 1024 + fidx);
#pragma unroll
    for (int j = 0; j < 4; ++j)
      bF[j] = *(const bf16x8*)((const char*)Bs + wc * 4096 + j * 1024 + fidx);
#pragma unroll
    for (int i = 0; i < 4; ++i)
#pragma unroll
      for (int j = 0; j < 4; ++j)
        acc[i][j] = __builtin_amdgcn_mfma_f32_16x16x32_bf16(aF[i], bF[j], acc[i][j], 0, 0, 0);
    __syncthreads();
  }

  // C/D layout: col = lane&15, row = (lane>>4)*4 + reg
  const int cm = wr * 64 + ((lane >> 4) << 2);
  const int cn = wc * 64 + (lane & 15);
  if (MODE == 0) {
#pragma unroll
    for (int i = 0; i < 4; ++i)
#pragma unroll
      for (int r = 0; r < 4; ++r) {
        const int m = m0 + cm + i * 16 + r;
        float rs = 0.f;
#pragma unroll
        for (int j = 0; j < 4; ++j) {
          const float e = __expf(fminf(acc[i][j][r] * 0.03125f, 30.0f));
          rs += e;
          Cb[(size_t)m * NS + n0 + cn + j * 16] = (__bf16)e;
        }
        rs += __shfl_xor(rs, 1, 64);
        rs += __shfl_xor(rs, 2, 64);
        rs += __shfl_xor(rs, 4, 64);
        rs += __shfl_xor(rs, 8, 64);
        if ((lane & 15) == 0) atomicAdd(&lsum[m], rs);
      }
  } else {
#pragma unroll
    for (int i = 0; i < 4; ++i)
#pragma unroll
      for (int r = 0; r < 4; ++r) {
        const int m = m0 + cm + i * 16 + r;
        const float inv = 1.0f / lsum[m];
#pragma unroll
        for (int j = 0; j < 4; ++j)
          Cf[(size_t)m * NS + n0 + cn + j * 16] = acc[i][j][r] * inv;
      }
  }
}

extern "C" void kernel_launch(void* const* d_in, const int* in_sizes, int n_in,
                              void* d_out, int out_size, void* d_ws, size_t ws_size,
                              hipStream_t stream) {
  const float* x = (const float*)d_in[0];  // [8192][1024] fp32
  const float* K = (const float*)d_in[1];  // [4096][1024] fp32
  const float* V = (const float*)d_in[2];  // [4096][1024] fp32
  float* out = (float*)d_out;              // [8192][1024] fp32

  char* ws = (char*)d_ws;
  __bf16* xb = (__bf16*)ws;                        // 16 MiB
  __bf16* Kb = (__bf16*)(ws + (16u << 20));        // 8 MiB
  __bf16* Vt = (__bf16*)(ws + (24u << 20));        // 8 MiB
  __bf16* P  = (__bf16*)(ws + (32u << 20));        // 64 MiB
  float*  l  = (float*)(ws + (96u << 20));         // 32 KiB

  f32_to_bf16_kernel<<<8192, 256, 0, stream>>>(x, xb, 8192 * 1024 / 4);
  f32_to_bf16_kernel<<<4096, 256, 0, stream>>>(K, Kb, 4096 * 1024 / 4);
  transpose_convert_kernel<<<dim3(64, 16), 256, 0, stream>>>(V, Vt);
  hipMemsetAsync(l, 0, 8192 * sizeof(float), stream);
  // P = exp(xb @ Kb^T / 32), fused row sums  (M=8192 N=4096 K=1024), 2048 blocks
  gemm_kernel<0, 1024, 4096><<<2048, 256, 0, stream>>>(xb, Kb, P, nullptr, l);
  // out = (P @ Vt-rows) / l  (M=8192 N=1024 K=4096), 512 blocks
  gemm_kernel<1, 4096, 1024><<<512, 256, 0, stream>>>(P, Vt, nullptr, out, l);
}

// Round 7
// 267.706 us; speedup vs baseline: 1.4525x; 1.0557x over previous
//
#include <hip/hip_runtime.h>
#include <hip/hip_bf16.h>

typedef __bf16 bf16x8 __attribute__((ext_vector_type(8)));
typedef __bf16 bf16x4 __attribute__((ext_vector_type(4)));
typedef float floatx4 __attribute__((ext_vector_type(4)));

typedef __attribute__((address_space(1))) const void gas_void;
typedef __attribute__((address_space(3))) void las_void;

__device__ inline void async_load16(const void* g, void* l) {
  __builtin_amdgcn_global_load_lds((gas_void*)g, (las_void*)l, 16, 0, 0);
}

// Fused preprocess: x->bf16 (blocks 0..2047), K->bf16 (2048..3071),
// V->Vt bf16 transpose (3072..4095), lsum zero (block 4096).
__global__ __launch_bounds__(256) void preprocess_kernel(
    const float* __restrict__ x, const float* __restrict__ Kp,
    const float* __restrict__ V, __bf16* __restrict__ xb,
    __bf16* __restrict__ Kb, __bf16* __restrict__ Vt,
    float* __restrict__ lsum) {
  const int b = blockIdx.x;
  const int t = threadIdx.x;
  if (b < 2048) {
#pragma unroll
    for (int k = 0; k < 4; ++k) {
      const int i = b * 1024 + k * 256 + t;
      float4 v = ((const float4*)x)[i];
      bf16x4 o = {(__bf16)v.x, (__bf16)v.y, (__bf16)v.z, (__bf16)v.w};
      ((bf16x4*)xb)[i] = o;
    }
  } else if (b < 3072) {
#pragma unroll
    for (int k = 0; k < 4; ++k) {
      const int i = (b - 2048) * 1024 + k * 256 + t;
      float4 v = ((const float4*)Kp)[i];
      bf16x4 o = {(__bf16)v.x, (__bf16)v.y, (__bf16)v.z, (__bf16)v.w};
      ((bf16x4*)Kb)[i] = o;
    }
  } else if (b < 4096) {
    __shared__ float tile[64][65];
    const int bb = b - 3072;
    const int bx = bb & 63, by = bb >> 6;
    for (int i = t; i < 64 * 64; i += 256) {
      const int r = i >> 6, c = i & 63;
      tile[r][c] = V[(size_t)(bx * 64 + r) * 1024 + by * 64 + c];
    }
    __syncthreads();
    for (int i = t; i < 64 * 64; i += 256) {
      const int r = i >> 6, c = i & 63;
      Vt[(size_t)(by * 64 + r) * 4096 + bx * 64 + c] = (__bf16)tile[c][r];
    }
  } else {
#pragma unroll
    for (int k = 0; k < 8; ++k)
      ((floatx4*)lsum)[k * 256 + t] = floatx4{0.f, 0.f, 0.f, 0.f};
  }
}

// C = A (MxK bf16, k-contig) x B (N rows of K bf16, k-contig). 128x128 tile, BK=64.
// LDS: XOR-swizzled layout; 16-B unit (row m, k-chunk q in 0..7) at unit index
// 8m + (q ^ (m&7)).
//  - staging: round r, thread t stages unit r*256+t: row m=r*32+(t>>3),
//    chunk q=(t&7)^(m&7) -> 8-lane groups read contiguous 128-B row segments.
//  - fragment reads: per 16-lane phase each 4-bank cluster hit exactly 2x (free).
//  - k-slice 1 address = slice-0 address ^ 64.
// Flat-1D grid + XCD swizzle (id%8 = XCD): blocks sharing an A m-tile share an XCD.
// MODE 0: P = exp(min(dot/32,30)) -> bf16 Cb + fused row-sum atomicAdd into lsum.
// MODE 1: out = dot / lsum[m] -> fp32 Cf.
template <int MODE, int KS, int NS>
__global__ __launch_bounds__(256) void gemm_kernel(const __bf16* __restrict__ A,
                                                   const __bf16* __restrict__ B,
                                                   __bf16* __restrict__ Cb,
                                                   float* __restrict__ Cf,
                                                   float* __restrict__ lsum) {
  constexpr int BK = 64;
  __shared__ __bf16 As[128 * BK];  // 16 KiB
  __shared__ __bf16 Bs[128 * BK];  // 16 KiB
  const int t = threadIdx.x;
  const int lane = t & 63;
  const int w = t >> 6;
  const int wr = w >> 1, wc = w & 1;

  const int id = blockIdx.x;
  const int g = id & 7;
  const int s = id >> 3;
  const int mt = g * 8 + (s & 7);
  const int nt = s >> 3;
  const int m0 = mt * 128;
  const int n0 = nt * 128;

  const __bf16* Ab = A + (size_t)m0 * KS;
  const __bf16* Bb = B + (size_t)n0 * KS;

  floatx4 acc[4][4] = {};

  // staging pointers: thread t handles rows r*32 + (t>>3), chunk (t&7)^((t>>3)&7)
  const int mA = t >> 3;
  const int qs = (t & 7) ^ (mA & 7);
  const __bf16* aP = Ab + (size_t)mA * KS + qs * 8;
  const __bf16* bP = Bb + (size_t)mA * KS + qs * 8;
  char* dA = (char*)As + t * 16;
  char* dB = (char*)Bs + t * 16;

  // fragment read offset (k-slice 0): m-low = rl, perm = qq ^ (rl&7)
  const int rl = lane & 15;
  const int qq = lane >> 4;
  const int fo = rl * 128 + ((qq ^ (rl & 7)) << 4);

  for (int k0 = 0; k0 < KS; k0 += BK) {
#pragma unroll
    for (int r = 0; r < 4; ++r) {
      async_load16(aP + (size_t)r * 32 * KS + k0, dA + r * 4096);
      async_load16(bP + (size_t)r * 32 * KS + k0, dB + r * 4096);
    }
    __builtin_amdgcn_s_waitcnt(0);
    __syncthreads();

    bf16x8 aF[4], bF[4];
#pragma unroll
    for (int i = 0; i < 4; ++i) {
      aF[i] = *(const bf16x8*)((const char*)As + wr * 8192 + i * 2048 + fo);
      bF[i] = *(const bf16x8*)((const char*)Bs + wc * 8192 + i * 2048 + fo);
    }
#pragma unroll
    for (int i = 0; i < 4; ++i)
#pragma unroll
      for (int j = 0; j < 4; ++j)
        acc[i][j] = __builtin_amdgcn_mfma_f32_16x16x32_bf16(aF[i], bF[j], acc[i][j], 0, 0, 0);
#pragma unroll
    for (int i = 0; i < 4; ++i) {
      aF[i] = *(const bf16x8*)((const char*)As + wr * 8192 + i * 2048 + (fo ^ 64));
      bF[i] = *(const bf16x8*)((const char*)Bs + wc * 8192 + i * 2048 + (fo ^ 64));
    }
#pragma unroll
    for (int i = 0; i < 4; ++i)
#pragma unroll
      for (int j = 0; j < 4; ++j)
        acc[i][j] = __builtin_amdgcn_mfma_f32_16x16x32_bf16(aF[i], bF[j], acc[i][j], 0, 0, 0);
    __syncthreads();
  }

  // C/D layout: col = lane&15, row = (lane>>4)*4 + reg
  const int cm = wr * 64 + ((lane >> 4) << 2);
  const int cn = wc * 64 + (lane & 15);
  if (MODE == 0) {
#pragma unroll
    for (int i = 0; i < 4; ++i)
#pragma unroll
      for (int r = 0; r < 4; ++r) {
        const int m = m0 + cm + i * 16 + r;
        float rs = 0.f;
#pragma unroll
        for (int j = 0; j < 4; ++j) {
          const float e = __expf(fminf(acc[i][j][r] * 0.03125f, 30.0f));
          rs += e;
          Cb[(size_t)m * NS + n0 + cn + j * 16] = (__bf16)e;
        }
        rs += __shfl_xor(rs, 1, 64);
        rs += __shfl_xor(rs, 2, 64);
        rs += __shfl_xor(rs, 4, 64);
        rs += __shfl_xor(rs, 8, 64);
        if ((lane & 15) == 0) atomicAdd(&lsum[m], rs);
      }
  } else {
#pragma unroll
    for (int i = 0; i < 4; ++i)
#pragma unroll
      for (int r = 0; r < 4; ++r) {
        const int m = m0 + cm + i * 16 + r;
        const float inv = 1.0f / lsum[m];
#pragma unroll
        for (int j = 0; j < 4; ++j)
          Cf[(size_t)m * NS + n0 + cn + j * 16] = acc[i][j][r] * inv;
      }
  }
}

extern "C" void kernel_launch(void* const* d_in, const int* in_sizes, int n_in,
                              void* d_out, int out_size, void* d_ws, size_t ws_size,
                              hipStream_t stream) {
  const float* x = (const float*)d_in[0];  // [8192][1024] fp32
  const float* K = (const float*)d_in[1];  // [4096][1024] fp32
  const float* V = (const float*)d_in[2];  // [4096][1024] fp32
  float* out = (float*)d_out;              // [8192][1024] fp32

  char* ws = (char*)d_ws;
  __bf16* xb = (__bf16*)ws;                        // 16 MiB
  __bf16* Kb = (__bf16*)(ws + (16u << 20));        // 8 MiB
  __bf16* Vt = (__bf16*)(ws + (24u << 20));        // 8 MiB
  __bf16* P  = (__bf16*)(ws + (32u << 20));        // 64 MiB
  float*  l  = (float*)(ws + (96u << 20));         // 32 KiB

  preprocess_kernel<<<4097, 256, 0, stream>>>(x, K, V, xb, Kb, Vt, l);
  // P = exp(xb @ Kb^T / 32), fused row sums  (M=8192 N=4096 K=1024), 2048 blocks
  gemm_kernel<0, 1024, 4096><<<2048, 256, 0, stream>>>(xb, Kb, P, nullptr, l);
  // out = (P @ Vt-rows) / l  (M=8192 N=1024 K=4096), 512 blocks
  gemm_kernel<1, 4096, 1024><<<512, 256, 0, stream>>>(P, Vt, nullptr, out, l);
}

// Round 8
// 258.883 us; speedup vs baseline: 1.5020x; 1.0341x over previous
//
#include <hip/hip_runtime.h>
#include <hip/hip_bf16.h>

typedef __bf16 bf16x8 __attribute__((ext_vector_type(8)));
typedef __bf16 bf16x4 __attribute__((ext_vector_type(4)));
typedef float floatx4 __attribute__((ext_vector_type(4)));

// Fused preprocess: x->bf16 (blocks 0..2047), K->bf16 (2048..3071),
// V->Vt bf16 transpose (3072..4095), lsum zero (block 4096).
__global__ __launch_bounds__(256) void preprocess_kernel(
    const float* __restrict__ x, const float* __restrict__ Kp,
    const float* __restrict__ V, __bf16* __restrict__ xb,
    __bf16* __restrict__ Kb, __bf16* __restrict__ Vt,
    float* __restrict__ lsum) {
  const int b = blockIdx.x;
  const int t = threadIdx.x;
  if (b < 2048) {
#pragma unroll
    for (int k = 0; k < 4; ++k) {
      const int i = b * 1024 + k * 256 + t;
      float4 v = ((const float4*)x)[i];
      bf16x4 o = {(__bf16)v.x, (__bf16)v.y, (__bf16)v.z, (__bf16)v.w};
      ((bf16x4*)xb)[i] = o;
    }
  } else if (b < 3072) {
#pragma unroll
    for (int k = 0; k < 4; ++k) {
      const int i = (b - 2048) * 1024 + k * 256 + t;
      float4 v = ((const float4*)Kp)[i];
      bf16x4 o = {(__bf16)v.x, (__bf16)v.y, (__bf16)v.z, (__bf16)v.w};
      ((bf16x4*)Kb)[i] = o;
    }
  } else if (b < 4096) {
    __shared__ float tile[64][65];
    const int bb = b - 3072;
    const int bx = bb & 63, by = bb >> 6;
    for (int i = t; i < 64 * 64; i += 256) {
      const int r = i >> 6, c = i & 63;
      tile[r][c] = V[(size_t)(bx * 64 + r) * 1024 + by * 64 + c];
    }
    __syncthreads();
    for (int i = t; i < 64 * 64; i += 256) {
      const int r = i >> 6, c = i & 63;
      Vt[(size_t)(by * 64 + r) * 4096 + bx * 64 + c] = (__bf16)tile[c][r];
    }
  } else {
#pragma unroll
    for (int k = 0; k < 8; ++k)
      ((floatx4*)lsum)[k * 256 + t] = floatx4{0.f, 0.f, 0.f, 0.f};
  }
}

// C = A (MxK bf16, k-contig) x B (N rows of K bf16, k-contig). 128x128 tile, BK=64.
// AITER-style register-staged pipeline (NOT global_load_lds): buffer loads for
// tile k+1 go to VGPRs and stay in flight across the barriers; s_barrier only
// needs the ds_write lgkm drain, so global latency is hidden by the MFMA block.
// LDS: XOR-swizzled; 16-B unit (row m, k-chunk q in 0..7) at unit 8m + (q^(m&7)).
//  - staging thread t owns rows {r*32 + t>>3}, chunk (t&7)^((t>>3)&7); writes
//    LDS at t*16 + r*4096 (consecutive lanes -> consecutive 16 B: conflict-free).
//  - fragment reads conflict-free (verified round 7: SQ_LDS_BANK_CONFLICT = 0).
//  - k-slice 1 address = slice-0 address ^ 64.
// Flat-1D grid + XCD swizzle (id%8 = XCD): blocks sharing an A m-tile share an XCD.
// MODE 0: P = exp(min(dot/32,30)) -> bf16 Cb + fused row-sum atomicAdd into lsum.
// MODE 1: out = dot / lsum[m] -> fp32 Cf.
template <int MODE, int KS, int NS>
__global__ __launch_bounds__(256) void gemm_kernel(const __bf16* __restrict__ A,
                                                   const __bf16* __restrict__ B,
                                                   __bf16* __restrict__ Cb,
                                                   float* __restrict__ Cf,
                                                   float* __restrict__ lsum) {
  constexpr int BK = 64;
  __shared__ __bf16 As[128 * BK];  // 16 KiB
  __shared__ __bf16 Bs[128 * BK];  // 16 KiB
  const int t = threadIdx.x;
  const int lane = t & 63;
  const int w = t >> 6;
  const int wr = w >> 1, wc = w & 1;

  const int id = blockIdx.x;
  const int g = id & 7;
  const int s = id >> 3;
  const int mt = g * 8 + (s & 7);
  const int nt = s >> 3;
  const int m0 = mt * 128;
  const int n0 = nt * 128;

  const __bf16* Ab = A + (size_t)m0 * KS;
  const __bf16* Bb = B + (size_t)n0 * KS;

  floatx4 acc[4][4] = {};

  // staging: thread t -> rows r*32 + (t>>3), chunk (t&7)^((t>>3)&7)
  const int mA = t >> 3;
  const int qs = (t & 7) ^ (mA & 7);
  const __bf16* aP = Ab + (size_t)mA * KS + qs * 8;
  const __bf16* bP = Bb + (size_t)mA * KS + qs * 8;
  char* dA = (char*)As + t * 16;
  char* dB = (char*)Bs + t * 16;

  // fragment read offset (k-slice 0)
  const int rl = lane & 15;
  const int qq = lane >> 4;
  const int fo = rl * 128 + ((qq ^ (rl & 7)) << 4);

  // preload tile 0 into registers
  bf16x8 sA[4], sB[4];
#pragma unroll
  for (int r = 0; r < 4; ++r) {
    sA[r] = *(const bf16x8*)(aP + (size_t)r * 32 * KS);
    sB[r] = *(const bf16x8*)(bP + (size_t)r * 32 * KS);
  }

  for (int k0 = 0; k0 < KS; k0 += BK) {
    // commit staged regs to LDS (ds_write_b128 x8)
#pragma unroll
    for (int r = 0; r < 4; ++r) {
      *(bf16x8*)(dA + r * 4096) = sA[r];
      *(bf16x8*)(dB + r * 4096) = sB[r];
    }
    __syncthreads();

    // issue next tile's global loads; they stay in flight through the MFMAs
    if (k0 + BK < KS) {
#pragma unroll
      for (int r = 0; r < 4; ++r) {
        sA[r] = *(const bf16x8*)(aP + (size_t)r * 32 * KS + k0 + BK);
        sB[r] = *(const bf16x8*)(bP + (size_t)r * 32 * KS + k0 + BK);
      }
    }

    bf16x8 aF[4], bF[4];
#pragma unroll
    for (int i = 0; i < 4; ++i) {
      aF[i] = *(const bf16x8*)((const char*)As + wr * 8192 + i * 2048 + fo);
      bF[i] = *(const bf16x8*)((const char*)Bs + wc * 8192 + i * 2048 + fo);
    }
#pragma unroll
    for (int i = 0; i < 4; ++i)
#pragma unroll
      for (int j = 0; j < 4; ++j)
        acc[i][j] = __builtin_amdgcn_mfma_f32_16x16x32_bf16(aF[i], bF[j], acc[i][j], 0, 0, 0);
#pragma unroll
    for (int i = 0; i < 4; ++i) {
      aF[i] = *(const bf16x8*)((const char*)As + wr * 8192 + i * 2048 + (fo ^ 64));
      bF[i] = *(const bf16x8*)((const char*)Bs + wc * 8192 + i * 2048 + (fo ^ 64));
    }
#pragma unroll
    for (int i = 0; i < 4; ++i)
#pragma unroll
      for (int j = 0; j < 4; ++j)
        acc[i][j] = __builtin_amdgcn_mfma_f32_16x16x32_bf16(aF[i], bF[j], acc[i][j], 0, 0, 0);
    __syncthreads();
  }

  // C/D layout: col = lane&15, row = (lane>>4)*4 + reg
  const int cm = wr * 64 + ((lane >> 4) << 2);
  const int cn = wc * 64 + (lane & 15);
  if (MODE == 0) {
#pragma unroll
    for (int i = 0; i < 4; ++i)
#pragma unroll
      for (int r = 0; r < 4; ++r) {
        const int m = m0 + cm + i * 16 + r;
        float rs = 0.f;
#pragma unroll
        for (int j = 0; j < 4; ++j) {
          const float e = __expf(fminf(acc[i][j][r] * 0.03125f, 30.0f));
          rs += e;
          Cb[(size_t)m * NS + n0 + cn + j * 16] = (__bf16)e;
        }
        rs += __shfl_xor(rs, 1, 64);
        rs += __shfl_xor(rs, 2, 64);
        rs += __shfl_xor(rs, 4, 64);
        rs += __shfl_xor(rs, 8, 64);
        if ((lane & 15) == 0) atomicAdd(&lsum[m], rs);
      }
  } else {
#pragma unroll
    for (int i = 0; i < 4; ++i)
#pragma unroll
      for (int r = 0; r < 4; ++r) {
        const int m = m0 + cm + i * 16 + r;
        const float inv = 1.0f / lsum[m];
#pragma unroll
        for (int j = 0; j < 4; ++j)
          Cf[(size_t)m * NS + n0 + cn + j * 16] = acc[i][j][r] * inv;
      }
  }
}

extern "C" void kernel_launch(void* const* d_in, const int* in_sizes, int n_in,
                              void* d_out, int out_size, void* d_ws, size_t ws_size,
                              hipStream_t stream) {
  const float* x = (const float*)d_in[0];  // [8192][1024] fp32
  const float* K = (const float*)d_in[1];  // [4096][1024] fp32
  const float* V = (const float*)d_in[2];  // [4096][1024] fp32
  float* out = (float*)d_out;              // [8192][1024] fp32

  char* ws = (char*)d_ws;
  __bf16* xb = (__bf16*)ws;                        // 16 MiB
  __bf16* Kb = (__bf16*)(ws + (16u << 20));        // 8 MiB
  __bf16* Vt = (__bf16*)(ws + (24u << 20));        // 8 MiB
  __bf16* P  = (__bf16*)(ws + (32u << 20));        // 64 MiB
  float*  l  = (float*)(ws + (96u << 20));         // 32 KiB

  preprocess_kernel<<<4097, 256, 0, stream>>>(x, K, V, xb, Kb, Vt, l);
  // P = exp(xb @ Kb^T / 32), fused row sums  (M=8192 N=4096 K=1024), 2048 blocks
  gemm_kernel<0, 1024, 4096><<<2048, 256, 0, stream>>>(xb, Kb, P, nullptr, l);
  // out = (P @ Vt-rows) / l  (M=8192 N=1024 K=4096), 512 blocks
  gemm_kernel<1, 4096, 1024><<<512, 256, 0, stream>>>(P, Vt, nullptr, out, l);
}